// Round 11
// baseline (84.942 us; speedup 1.0000x reference)
//
#include <hip/hip_runtime.h>

#define NB 32
#define CD 64
#define HH 64
#define WW 64
#define KK 512
#define HW (HH * WW)
#define NPIX (NB * HH * WW)      // 131072 pixels
#define BCHW (NB * CD * HH * WW) // 8388608 elements per big output

typedef __attribute__((ext_vector_type(8))) short bf16x8;
typedef __attribute__((ext_vector_type(4))) float f32x4;

__device__ inline unsigned short f2bf(float f) { // RTNE fp32 -> bf16 bits
  unsigned u = __float_as_uint(f);
  return (unsigned short)((u + 0x7FFFu + ((u >> 16) & 1u)) >> 16);
}

// ---------------------------------------------------------------------------
// Prep: emb (512x64 fp32) -> bf16 fragments in MFMA A-operand order, GLOBAL.
// Entry e: lane=e&63, kstep s=(e>>6)&1, tile t=e>>7;
// code = 16t+(lane&15), channels = 32s + 8*(lane>>4) + j. L2-resident (64 KB).
// ---------------------------------------------------------------------------
__global__ __launch_bounds__(256) void vq_prep(const float* __restrict__ emb,
                                               short* __restrict__ embfrag) {
  int e = blockIdx.x * 256 + threadIdx.x; // 4096 frag entries
  int el = e & 63, s = (e >> 6) & 1, t = e >> 7;
  const float* ep = emb + (t * 16 + (el & 15)) * CD + s * 32 + (el >> 4) * 8;
  float4 f0 = *(const float4*)ep;
  float4 f1 = *(const float4*)(ep + 4);
  bf16x8 v;
  v[0] = (short)f2bf(f0.x); v[1] = (short)f2bf(f0.y);
  v[2] = (short)f2bf(f0.z); v[3] = (short)f2bf(f0.w);
  v[4] = (short)f2bf(f1.x); v[5] = (short)f2bf(f1.y);
  v[6] = (short)f2bf(f1.z); v[7] = (short)f2bf(f1.w);
  *(bf16x8*)(embfrag + e * 8) = v;
}

// ---------------------------------------------------------------------------
// Fully-fused kernel, K-split x4. 1024 blocks x 512 thr (8 waves, 128 px).
// Wave wv: pixel-group pg = wv&1 (64 px), K-quarter kh = wv>>1 (8 tiles).
// Fusion re-attempt with all three prior failure causes removed:
//   R4 cause (64KB LDS -> 2 blk/CU) -> <1 KB LDS here (embfrag stays L2).
//   R5 cause (2048-wave grid, 25% cap) -> 8192 waves = 100% of slots.
//   R6 cause (halved MFMA:load reuse) -> K-split preserves reuse + traffic.
// Packed-key argmax: key = (bits(16+x.e) & ~0x1FF) | (511-code)
//   [uint argmax == float argmax (all-positive); first-index tie rule;
//    e^2 <= 2.4e-4 dropped — below the 2^-10 pack quantum, near-ties only].
// Epilogue (no z round-trip): LDS zbuf -> BHWC min_index (contiguous float4
// stores, 16-lane coalesced row gathers) + BCHW quantized (lane=pixel,
// wave = 16ch x 64px, 256B-coalesced stores) + fixed-point loss atomic +
// last-block ticket finalize.
// ---------------------------------------------------------------------------
__global__ __launch_bounds__(512) void vq_fused(
    const float* __restrict__ x, const float* __restrict__ emb,
    const short* __restrict__ embfrag,
    float* __restrict__ outq, float* __restrict__ outm,
    float* __restrict__ outs,
    unsigned long long* __restrict__ cnt, unsigned* __restrict__ ticket) {
  __shared__ unsigned lkeys[8][64];
  __shared__ int zbuf[128];
  __shared__ float wsum[2];

  const int tid = threadIdx.x;
  const int l = tid & 63, wv = tid >> 6;
  const int g = l >> 4, li = l & 15;
  const int pg = wv & 1, kh = wv >> 1;

  const int bpix0 = blockIdx.x * 128;       // block's first pixel
  const int b = bpix0 >> 12;
  const int hw0 = (bpix0 & 4095) + pg * 64; // wave's first hw
  const float* xb = x + (size_t)b * (CD * HW) + hw0 + li;

  // ---- x -> B-frags (col=lane&15=pixel) + ||x||^2 partial ----
  bf16x8 xb0[4], xb1[4];
  float xxpart = 0.f;
#pragma unroll
  for (int mt = 0; mt < 4; ++mt) {
    const float* xp = xb + mt * 16;
#pragma unroll
    for (int j = 0; j < 8; ++j) {
      float v0 = xp[(g * 8 + j) * HW];
      float v1 = xp[(32 + g * 8 + j) * HW];
      xxpart = fmaf(v0, v0, fmaf(v1, v1, xxpart));
      xb0[mt][j] = (short)f2bf(v0);
      xb1[mt][j] = (short)f2bf(v1);
    }
  }

  // ---- MFMA over this wave's 8 code-tiles ----
  const bf16x8* __restrict__ lf = (const bf16x8*)embfrag;
  unsigned bestkey[4] = {0u, 0u, 0u, 0u};
  const int tbase = kh * 8;
  const int P = 511 - 4 * g; // 511 - code = P - 16t - q

#pragma unroll 4
  for (int tt = 0; tt < 8; ++tt) {
    const int t = tbase + tt;
    bf16x8 A0 = lf[(t * 2 + 0) * 64 + l];
    bf16x8 A1 = lf[(t * 2 + 1) * 64 + l];
    const unsigned cb = (unsigned)(P - 16 * t);
#pragma unroll
    for (int mt = 0; mt < 4; ++mt) {
      f32x4 acc = {16.f, 16.f, 16.f, 16.f};
      acc = __builtin_amdgcn_mfma_f32_16x16x32_bf16(A0, xb0[mt], acc, 0, 0, 0);
      acc = __builtin_amdgcn_mfma_f32_16x16x32_bf16(A1, xb1[mt], acc, 0, 0, 0);
      unsigned k0 = (__float_as_uint(acc[0]) & 0xFFFFFE00u) | cb;
      unsigned k1 = (__float_as_uint(acc[1]) & 0xFFFFFE00u) | (cb - 1u);
      unsigned k2 = (__float_as_uint(acc[2]) & 0xFFFFFE00u) | (cb - 2u);
      unsigned k3 = (__float_as_uint(acc[3]) & 0xFFFFFE00u) | (cb - 3u);
      unsigned m01 = k0 > k1 ? k0 : k1;
      unsigned m23 = k2 > k3 ? k2 : k3;
      unsigned mm = m01 > m23 ? m01 : m23;
      bestkey[mt] = mm > bestkey[mt] ? mm : bestkey[mt];
    }
  }

  // ---- cross-g butterfly -> per-pixel key for this K-quarter ----
#pragma unroll
  for (int mt = 0; mt < 4; ++mt) {
    unsigned k = bestkey[mt];
    unsigned k1 = (unsigned)__shfl_xor((int)k, 16, 64);
    k = k < k1 ? k1 : k;
    k1 = (unsigned)__shfl_xor((int)k, 32, 64);
    k = k < k1 ? k1 : k;
    if (g == 0) lkeys[wv][mt * 16 + li] = k;
  }
  __syncthreads();

  // ---- merge the 4 K-quarters; zbuf + loss partial (kh==0 waves) ----
  if (kh == 0) {
    unsigned k = lkeys[pg][l];
    unsigned kq = lkeys[pg + 2][l];
    k = k < kq ? kq : k;
    kq = lkeys[pg + 4][l];
    k = k < kq ? kq : k;
    kq = lkeys[pg + 6][l];
    k = k < kq ? kq : k;
    zbuf[pg * 64 + l] = 511 - (int)(k & 511u);
    float best = __uint_as_float(k & 0xFFFFFE00u) - 16.f; // best x.e
    float v = fmaf(best, -2.f, xxpart);
#pragma unroll
    for (int off = 32; off > 0; off >>= 1) v += __shfl_down(v, off, 64);
    if (l == 0) wsum[pg] = v;
  }
  __syncthreads(); // zbuf + wsum ready

  if (tid == 0) {
    double p = (double)(wsum[0] + wsum[1]);
    atomicAdd(cnt, (unsigned long long)(long long)(p * 1048576.0 + 0.5));
  }

  // ---- min_index write, BHWC flat: block region = 32 KB contiguous ----
  float4* __restrict__ mo4 = (float4*)(outm + (size_t)bpix0 * CD);
#pragma unroll
  for (int i = 0; i < 4; ++i) {
    int f = i * 512 + tid;      // float4 index in [0, 2048)
    int px = f >> 4;            // 16 lanes share a pixel -> row gather
    int c0 = (f & 15) * 4;      //   is 64 consecutive floats, coalesced
    int code = zbuf[px];
    mo4[f] = *(const float4*)(emb + code * CD + c0);
  }

  // ---- quantized write, BCHW: lane=pixel, wave = 16 ch x 64 px ----
  {
    int code = zbuf[pg * 64 + l];
    const float4* __restrict__ er = (const float4*)(emb + code * CD) + kh * 4;
    float* qo = outq + (size_t)b * (CD * HW) + (size_t)(kh * 16) * HW + hw0 + l;
#pragma unroll
    for (int cg = 0; cg < 4; ++cg) {
      float4 vv = er[cg];
      qo[(4 * cg + 0) * HW] = vv.x;
      qo[(4 * cg + 1) * HW] = vv.y;
      qo[(4 * cg + 2) * HW] = vv.z;
      qo[(4 * cg + 3) * HW] = vv.w;
    }
  }

  // ---- last block finalizes losses ----
  if (tid == 0) {
    __threadfence();
    unsigned done = atomicAdd(ticket, 1u);
    if (done == (unsigned)gridDim.x - 1u) {
      __threadfence();
      unsigned long long tot = atomicAdd(cnt, 0ULL); // coherent read
      float L = (float)((double)(long long)tot / (1048576.0 * (double)BCHW));
      outs[0] = L;        // codebook_loss
      outs[1] = L;        // commitment_loss
      outs[2] = 1.2f * L; // quantizer_loss
    }
  }
}

extern "C" void kernel_launch(void* const* d_in, const int* in_sizes, int n_in,
                              void* d_out, int out_size, void* d_ws, size_t ws_size,
                              hipStream_t stream) {
  const float* x = (const float*)d_in[0];
  const float* emb = (const float*)d_in[1];
  float* out = (float*)d_out;

  short* embfrag = (short*)d_ws;                              // 64 KB
  unsigned long long* cnt = (unsigned long long*)((char*)d_ws + 65536);
  unsigned* ticket = (unsigned*)((char*)d_ws + 65536 + 8);

  hipMemsetAsync((char*)d_ws + 65536, 0, 16, stream); // zero cnt + ticket
  vq_prep<<<16, 256, 0, stream>>>(emb, embfrag);
  vq_fused<<<NPIX / 128, 512, 0, stream>>>(x, emb, embfrag, out,
                                           out + BCHW + 3, out + BCHW,
                                           cnt, ticket);
}

// Round 14
// 43.711 us; speedup vs baseline: 1.9433x; 1.9433x over previous
//
#include <hip/hip_runtime.h>

#define NB 32
#define CD 64
#define HH 64
#define WW 64
#define KK 512
#define HW (HH * WW)
#define NPIX (NB * HH * WW)      // 131072 pixels
#define BCHW (NB * CD * HH * WW) // 8388608 elements per big output
#define QBLOCKS (NB * CD)        // 2048 blocks for quantized write
#define MIBLOCKS (BCHW / 1024)   // 8192 blocks for min_index write (float4)
#define ABLOCKS (NPIX / 256)     // 512 argmin blocks

typedef __attribute__((ext_vector_type(8))) short bf16x8;
typedef __attribute__((ext_vector_type(4))) float f32x4;

__device__ inline unsigned short f2bf(float f) { // RTNE fp32 -> bf16 bits
  unsigned u = __float_as_uint(f);
  return (unsigned short)((u + 0x7FFFu + ((u >> 16) & 1u)) >> 16);
}

// ---------------------------------------------------------------------------
// Prep: emb (512x64 fp32) -> bf16 fragments in MFMA A-operand order, GLOBAL.
// Entry e: lane=e&63, kstep s=(e>>6)&1, tile t=e>>7;
// code = 16t+(lane&15), channels = 32s + 8*(lane>>4) + j. L2-resident (64 KB).
// ---------------------------------------------------------------------------
__global__ __launch_bounds__(256) void vq_prep(const float* __restrict__ emb,
                                               short* __restrict__ embfrag) {
  int e = blockIdx.x * 256 + threadIdx.x; // 4096 frag entries
  int el = e & 63, s = (e >> 6) & 1, t = e >> 7;
  const float* ep = emb + (t * 16 + (el & 15)) * CD + s * 32 + (el >> 4) * 8;
  float4 f0 = *(const float4*)ep;
  float4 f1 = *(const float4*)(ep + 4);
  bf16x8 v;
  v[0] = (short)f2bf(f0.x); v[1] = (short)f2bf(f0.y);
  v[2] = (short)f2bf(f0.z); v[3] = (short)f2bf(f0.w);
  v[4] = (short)f2bf(f1.x); v[5] = (short)f2bf(f1.y);
  v[6] = (short)f2bf(f1.z); v[7] = (short)f2bf(f1.w);
  *(bf16x8*)(embfrag + e * 8) = v;
}

// ---------------------------------------------------------------------------
// Lean argmin, K-split x2 — the R7 structure that set the 48.2us best.
// 512 blocks x 512 threads (8 waves). Wave wv: pixel-group pg = wv&3
// (64 px), K-half kh = wv>>2 (16 of 32 code-tiles). K-split doubles waves
// (4096) without changing total embfrag traffic or per-wave MFMA:load reuse.
// Packed-key argmax: key = (bits(16+x.e) & ~0x1FF) | (511-code)
//   [uint argmax == float argmax (all-positive); first-index tie rule;
//    e^2 <= 2.4e-4 dropped — below the 2^-10 pack quantum, near-ties only].
// Halves merge via LDS; kh==0 waves write z; per-block loss partial is a
// PLAIN store — next dispatch reads it coherently (kernel boundary flush,
// proven by z itself in R7/R9). R12 lesson: no atomics/memset needed at all.
// ---------------------------------------------------------------------------
__global__ __launch_bounds__(512) void vq_argmin(
    const float* __restrict__ x, const short* __restrict__ embfrag,
    int* __restrict__ z, float* __restrict__ partial) {
  __shared__ unsigned lkeys[8][64];
  __shared__ float wsum[4];

  const int tid = threadIdx.x;
  const int l = tid & 63, wv = tid >> 6;
  const int g = l >> 4, li = l & 15;
  const int pg = wv & 3, kh = wv >> 2;

  // ---- x -> B-frags (col=lane&15=pixel) + ||x||^2 partial ----
  const int npix0 = (blockIdx.x * 4 + pg) * 64;
  const int b = npix0 >> 12, hw0 = npix0 & 4095;
  const float* xb = x + (size_t)b * (CD * HW) + hw0 + li;
  bf16x8 xb0[4], xb1[4];
  float xxpart = 0.f;
#pragma unroll
  for (int mt = 0; mt < 4; ++mt) {
    const float* xp = xb + mt * 16;
#pragma unroll
    for (int j = 0; j < 8; ++j) {
      float v0 = xp[(g * 8 + j) * HW];
      float v1 = xp[(32 + g * 8 + j) * HW];
      xxpart = fmaf(v0, v0, fmaf(v1, v1, xxpart));
      xb0[mt][j] = (short)f2bf(v0);
      xb1[mt][j] = (short)f2bf(v1);
    }
  }

  // ---- MFMA over this wave's 16 code-tiles ----
  const bf16x8* __restrict__ lf = (const bf16x8*)embfrag;
  unsigned bestkey[4] = {0u, 0u, 0u, 0u};
  const int tbase = kh * 16;
  const int P = 511 - 4 * g; // 511 - code = P - 16t - q

#pragma unroll 4
  for (int tt = 0; tt < 16; ++tt) {
    const int t = tbase + tt;
    bf16x8 A0 = lf[(t * 2 + 0) * 64 + l];
    bf16x8 A1 = lf[(t * 2 + 1) * 64 + l];
    const unsigned cb = (unsigned)(P - 16 * t);
#pragma unroll
    for (int mt = 0; mt < 4; ++mt) {
      f32x4 acc = {16.f, 16.f, 16.f, 16.f};
      acc = __builtin_amdgcn_mfma_f32_16x16x32_bf16(A0, xb0[mt], acc, 0, 0, 0);
      acc = __builtin_amdgcn_mfma_f32_16x16x32_bf16(A1, xb1[mt], acc, 0, 0, 0);
      unsigned k0 = (__float_as_uint(acc[0]) & 0xFFFFFE00u) | cb;
      unsigned k1 = (__float_as_uint(acc[1]) & 0xFFFFFE00u) | (cb - 1u);
      unsigned k2 = (__float_as_uint(acc[2]) & 0xFFFFFE00u) | (cb - 2u);
      unsigned k3 = (__float_as_uint(acc[3]) & 0xFFFFFE00u) | (cb - 3u);
      unsigned m01 = k0 > k1 ? k0 : k1;
      unsigned m23 = k2 > k3 ? k2 : k3;
      unsigned mm = m01 > m23 ? m01 : m23;
      bestkey[mt] = mm > bestkey[mt] ? mm : bestkey[mt];
    }
  }

  // ---- cross-g butterfly (4 g-groups) -> per-pixel key for this K-half ----
#pragma unroll
  for (int mt = 0; mt < 4; ++mt) {
    unsigned k = bestkey[mt];
    unsigned k1 = (unsigned)__shfl_xor((int)k, 16, 64);
    k = k < k1 ? k1 : k;
    k1 = (unsigned)__shfl_xor((int)k, 32, 64);
    k = k < k1 ? k1 : k;
    if (g == 0) lkeys[wv][mt * 16 + li] = k;
  }
  __syncthreads();

  // ---- merge K-halves; z write + loss partial (kh==0 waves only) ----
  if (kh == 0) {
    unsigned m0 = lkeys[wv][l], m1 = lkeys[wv + 4][l];
    unsigned k = m0 > m1 ? m0 : m1;
    z[npix0 + l] = 511 - (int)(k & 511u);
    float best = __uint_as_float(k & 0xFFFFFE00u) - 16.f; // best x.e
    float v = fmaf(best, -2.f, xxpart);
#pragma unroll
    for (int off = 32; off > 0; off >>= 1) v += __shfl_down(v, off, 64);
    if (l == 0) wsum[wv] = v;
  }
  __syncthreads();
  if (tid == 0)
    partial[blockIdx.x] = (wsum[0] + wsum[1]) + (wsum[2] + wsum[3]);
}

// ---------------------------------------------------------------------------
// Wide write kernel: 10240 blocks.
//  blocks [0, 2048): quantized BCHW — block=(b,c), emb[:,c] staged in LDS,
//    int4 z loads + LDS gather + float4 coalesced stores.
//  blocks [2048, 10240): min_index BHWC — thread=float4 elem, 16 lanes/px,
//    emb row gather (L2) + 1KB/wave coalesced stores.
//  block 0 wave 0 sums the 512 plain-stored partials -> the 3 losses
//  (cross-dispatch plain-store coherence proven by the z path itself).
// ---------------------------------------------------------------------------
__global__ __launch_bounds__(256) void vq_write(
    const float* __restrict__ emb, const int* __restrict__ z,
    float* __restrict__ outq, float* __restrict__ outm,
    const float* __restrict__ partial, float* __restrict__ outs) {
  __shared__ float ecol[KK];
  const int tid = threadIdx.x;
  if (blockIdx.x == 0 && tid < 64) {
    float s = 0.f;
#pragma unroll
    for (int j = 0; j < ABLOCKS / 64; ++j) s += partial[j * 64 + tid];
#pragma unroll
    for (int off = 32; off > 0; off >>= 1) s += __shfl_down(s, off, 64);
    if (tid == 0) {
      float L = s / (float)BCHW;
      outs[0] = L;        // codebook_loss
      outs[1] = L;        // commitment_loss
      outs[2] = 1.2f * L; // quantizer_loss
    }
  }
  if (blockIdx.x < QBLOCKS) {
    const int b = blockIdx.x >> 6;
    const int c = blockIdx.x & 63;
    for (int k = tid; k < KK; k += 256) ecol[k] = emb[k * CD + c];
    __syncthreads();
    const int4* __restrict__ zb4 = (const int4*)(z + b * HW);
    float4* __restrict__ ob4 = (float4*)(outq + (size_t)(b * CD + c) * HW);
#pragma unroll
    for (int i = tid; i < HW / 4; i += 256) {
      int4 zz = zb4[i];
      float4 vv = {ecol[zz.x], ecol[zz.y], ecol[zz.z], ecol[zz.w]};
      ob4[i] = vv;
    }
  } else {
    const int f = (blockIdx.x - QBLOCKS) * 256 + tid; // float4 index
    const int px = f >> 4;
    const int c0 = (f & 15) * 4;
    const int code = z[px];
    float4 vv = *(const float4*)(emb + code * CD + c0);
    ((float4*)outm)[f] = vv;
  }
}

extern "C" void kernel_launch(void* const* d_in, const int* in_sizes, int n_in,
                              void* d_out, int out_size, void* d_ws, size_t ws_size,
                              hipStream_t stream) {
  const float* x = (const float*)d_in[0];
  const float* emb = (const float*)d_in[1];
  float* out = (float*)d_out;

  short* embfrag = (short*)d_ws;                                   // 64 KB
  int* z = (int*)((char*)d_ws + 65536);                            // 512 KB
  float* partial = (float*)((char*)d_ws + 65536 + NPIX * sizeof(int)); // 2 KB

  vq_prep<<<16, 256, 0, stream>>>(emb, embfrag);
  vq_argmin<<<ABLOCKS, 512, 0, stream>>>(x, embfrag, z, partial);
  vq_write<<<QBLOCKS + MIBLOCKS, 256, 0, stream>>>(emb, z, out, out + BCHW + 3,
                                                   partial, out + BCHW);
}